// Round 1
// baseline (192.408 us; speedup 1.0000x reference)
//
#include <hip/hip_runtime.h>
#include <math.h>

// ---------------- device math helpers ----------------
__device__ __forceinline__ float sigmoidf_(float x) {
    return 1.0f / (1.0f + __expf(-x) * 0.0f + expf(-x)); // keep plain expf
}
__device__ __forceinline__ float sigmf(float x) {
    return 1.0f / (1.0f + expf(-x));
}
__device__ __forceinline__ float softplusf(float x) {          // log(1+e^x)
    return fmaxf(x, 0.0f) + log1pf(expf(-fabsf(x)));
}
__device__ __forceinline__ float logsigmoidf(float x) {        // -softplus(-x)
    return fminf(x, 0.0f) - log1pf(expf(-fabsf(x)));
}

// ---------------- negative-part kernel ----------------
// Grid-stride over float4 chunks of all three levels concatenated.
// out[1] += sum(softplus(l)*sig(l)^2 * negmask * factor)
// out[3] += sum(sig(l)^2 * negmask)
__global__ __launch_bounds__(256) void focal_neg_kernel(
    const float4* __restrict__ lg0, const float4* __restrict__ pr0, int n0,
    const float4* __restrict__ lg1, const float4* __restrict__ pr1, int n1,
    const float4* __restrict__ lg2, const float4* __restrict__ pr2, int n2,
    float* __restrict__ out)
{
    float loss = 0.0f, cnt = 0.0f;
    const int total = n0 + n1 + n2;
    const int stride = gridDim.x * blockDim.x;
    for (int i = blockIdx.x * blockDim.x + threadIdx.x; i < total; i += stride) {
        const float4* lgp; const float4* prp; int idx; float factor;
        if (i < n0)           { lgp = lg0; prp = pr0; idx = i;            factor = 4.0f; }
        else if (i < n0 + n1) { lgp = lg1; prp = pr1; idx = i - n0;       factor = 2.0f; }
        else                  { lgp = lg2; prp = pr2; idx = i - n0 - n1;  factor = 1.0f; }
        float4 l4 = lgp[idx];
        float4 p4 = prp[idx];
        const float* lv = (const float*)&l4;
        const float* pv = (const float*)&p4;
        #pragma unroll
        for (int j = 0; j < 4; ++j) {
            float l = lv[j];
            if (pv[j] == -1.0f) {
                float s = sigmf(l);
                float w = s * s;
                cnt  += w;
                loss += softplusf(l) * w * factor;
            }
        }
    }
    // wave (64-lane) reduce
    #pragma unroll
    for (int off = 32; off > 0; off >>= 1) {
        loss += __shfl_down(loss, off);
        cnt  += __shfl_down(cnt,  off);
    }
    __shared__ float sl[4], sc[4];        // 256 threads = 4 waves
    int wid  = threadIdx.x >> 6;
    int lane = threadIdx.x & 63;
    if (lane == 0) { sl[wid] = loss; sc[wid] = cnt; }
    __syncthreads();
    if (threadIdx.x == 0) {
        atomicAdd(&out[1], sl[0] + sl[1] + sl[2] + sl[3]);
        atomicAdd(&out[3], sc[0] + sc[1] + sc[2] + sc[3]);
    }
}

// ---------------- positive-part kernel ----------------
// 768 items = 3 levels x B(2) x P(128). One thread per item.
// window offs = arange(2r)-r  -> [c-r, c+r-1], size 2r per axis.
__global__ __launch_bounds__(256) void focal_pos_kernel(
    const float* __restrict__ lg0, const int* __restrict__ co0,
    const float* __restrict__ lg1, const int* __restrict__ co1,
    const float* __restrict__ lg2, const int* __restrict__ co2,
    float* __restrict__ out)
{
    int item = blockIdx.x * blockDim.x + threadIdx.x;   // 0..767
    float loss = 0.0f, cnt = 0.0f;
    if (item < 768) {
        int lvl = item >> 8;        // 256 items / level
        int rem = item & 255;
        int b   = rem >> 7;         // 0..1
        int p   = rem & 127;
        const float* lg; const int* co; int D; int r; float factor;
        if (lvl == 0)      { lg = lg0; co = co0; D = 128; r = 1; factor = 4.0f; }
        else if (lvl == 1) { lg = lg1; co = co1; D = 64;  r = 2; factor = 2.0f; }
        else               { lg = lg2; co = co2; D = 32;  r = 3; factor = 1.0f; }
        const int* c = co + (b * 128 + p) * 4;
        int a = c[0], y = c[1], x = c[2], z = c[3];
        if (a > -1) {
            const int A = 2;
            int ac = min(max(a, 0), A - 1);
            int yc = min(max(y, 0), D - 1);
            int xc = min(max(x, 0), D - 1);
            int zc = min(max(z, 0), D - 1);
            const float* base = lg + (size_t)(b * A + ac) * D * D * D;
            float wmax = -INFINITY;
            for (int dy = 0; dy < 2 * r; ++dy) {
                int iy = min(max(yc + dy - r, 0), D - 1);
                for (int dx = 0; dx < 2 * r; ++dx) {
                    int ix = min(max(xc + dx - r, 0), D - 1);
                    const float* row = base + ((size_t)iy * D + ix) * D;
                    for (int dz = 0; dz < 2 * r; ++dz) {
                        int iz = min(max(zc + dz - r, 0), D - 1);
                        wmax = fmaxf(wmax, row[iz]);
                    }
                }
            }
            float point = base[((size_t)yc * D + xc) * D + zc];
            bool near_low = (yc < r) || (xc < r) || (zc < r);
            float lp = near_low ? point : wmax;
            float s  = sigmf(lp);
            float omw = 1.0f - s;
            float w  = omw * omw;
            loss = -logsigmoidf(lp) * w * factor;
            cnt  = w;
        }
    }
    // wave reduce then one atomic per wave
    #pragma unroll
    for (int off = 32; off > 0; off >>= 1) {
        loss += __shfl_down(loss, off);
        cnt  += __shfl_down(cnt,  off);
    }
    if ((threadIdx.x & 63) == 0) {
        atomicAdd(&out[0], loss);
        atomicAdd(&out[2], cnt);
    }
}

extern "C" void kernel_launch(void* const* d_in, const int* in_sizes, int n_in,
                              void* d_out, int out_size, void* d_ws, size_t ws_size,
                              hipStream_t stream) {
    const float* lg[3]; const float* pr[3]; const int* co[3];
    int nElem[3];
    if (n_in == 9 && in_sizes[1] == in_sizes[0]) {
        // setup_inputs() dict order: lg0,pr0,co0, lg1,pr1,co1, lg2,pr2,co2
        lg[0] = (const float*)d_in[0]; pr[0] = (const float*)d_in[1]; co[0] = (const int*)d_in[2];
        lg[1] = (const float*)d_in[3]; pr[1] = (const float*)d_in[4]; co[1] = (const int*)d_in[5];
        lg[2] = (const float*)d_in[6]; pr[2] = (const float*)d_in[7]; co[2] = (const int*)d_in[8];
        nElem[0] = in_sizes[0]; nElem[1] = in_sizes[3]; nElem[2] = in_sizes[6];
    } else {
        // reference signature order: lg0,lg1,lg2, pr0,pr1,pr2, co0,co1,co2
        lg[0] = (const float*)d_in[0]; lg[1] = (const float*)d_in[1]; lg[2] = (const float*)d_in[2];
        pr[0] = (const float*)d_in[3]; pr[1] = (const float*)d_in[4]; pr[2] = (const float*)d_in[5];
        co[0] = (const int*)d_in[6];   co[1] = (const int*)d_in[7];   co[2] = (const int*)d_in[8];
        nElem[0] = in_sizes[0]; nElem[1] = in_sizes[1]; nElem[2] = in_sizes[2];
    }
    float* out = (float*)d_out;
    hipMemsetAsync(out, 0, 4 * sizeof(float), stream);

    int n0 = nElem[0] / 4, n1 = nElem[1] / 4, n2 = nElem[2] / 4;
    int total = n0 + n1 + n2;
    int blocks = (total + 255) / 256;
    if (blocks > 2048) blocks = 2048;
    focal_neg_kernel<<<blocks, 256, 0, stream>>>(
        (const float4*)lg[0], (const float4*)pr[0], n0,
        (const float4*)lg[1], (const float4*)pr[1], n1,
        (const float4*)lg[2], (const float4*)pr[2], n2,
        out);
    focal_pos_kernel<<<3, 256, 0, stream>>>(
        lg[0], co[0], lg[1], co[1], lg[2], co[2], out);
}

// Round 2
// 175.059 us; speedup vs baseline: 1.0991x; 1.0991x over previous
//
#include <hip/hip_runtime.h>
#include <math.h>

// ---------------- fast device math (HW transcendentals) ----------------
// tolerance is ~2% relative; v_exp_f32/v_log_f32/v_rcp_f32 are ~1 ulp.
__device__ __forceinline__ float fexp(float x)  { return __expf(x); }   // v_exp_f32
__device__ __forceinline__ float flog(float x)  { return __logf(x); }   // v_log_f32
__device__ __forceinline__ float frcp(float x)  { return __builtin_amdgcn_rcpf(x); }

// ---------------- negative-part kernel ----------------
// out[1] += sum(softplus(l) * sig(l)^2 * negmask * factor)
// out[3] += sum(sig(l)^2 * negmask)
__global__ __launch_bounds__(256) void focal_neg_kernel(
    const float4* __restrict__ lg0, const float4* __restrict__ pr0, int n0,
    const float4* __restrict__ lg1, const float4* __restrict__ pr1, int n1,
    const float4* __restrict__ lg2, const float4* __restrict__ pr2, int n2,
    float* __restrict__ out)
{
    float loss = 0.0f, cnt = 0.0f;
    const int total = n0 + n1 + n2;
    const int stride = gridDim.x * blockDim.x;
    for (int i = blockIdx.x * blockDim.x + threadIdx.x; i < total; i += stride) {
        const float4* lgp; const float4* prp; int idx; float factor;
        if (i < n0)           { lgp = lg0; prp = pr0; idx = i;            factor = 4.0f; }
        else if (i < n0 + n1) { lgp = lg1; prp = pr1; idx = i - n0;       factor = 2.0f; }
        else                  { lgp = lg2; prp = pr2; idx = i - n0 - n1;  factor = 1.0f; }
        float4 l4 = lgp[idx];
        float4 p4 = prp[idx];
        const float* lv = (const float*)&l4;
        const float* pv = (const float*)&p4;
        #pragma unroll
        for (int j = 0; j < 4; ++j) {
            float l = lv[j];
            float m = (pv[j] == -1.0f) ? 1.0f : 0.0f;     // branchless mask
            float t = fexp(-fabsf(l));                    // e^{-|l|}, one v_exp
            float inv = frcp(1.0f + t);                   // one v_rcp
            float s = (l >= 0.0f) ? inv : t * inv;        // sigmoid(l)
            float w = s * s * m;
            float sp = fmaxf(l, 0.0f) + flog(1.0f + t);   // softplus(l), one v_log
            cnt  += w;
            loss += sp * w * factor;
        }
    }
    // wave (64-lane) reduce
    #pragma unroll
    for (int off = 32; off > 0; off >>= 1) {
        loss += __shfl_down(loss, off);
        cnt  += __shfl_down(cnt,  off);
    }
    __shared__ float sl[4], sc[4];        // 256 threads = 4 waves
    int wid  = threadIdx.x >> 6;
    int lane = threadIdx.x & 63;
    if (lane == 0) { sl[wid] = loss; sc[wid] = cnt; }
    __syncthreads();
    if (threadIdx.x == 0) {
        atomicAdd(&out[1], sl[0] + sl[1] + sl[2] + sl[3]);
        atomicAdd(&out[3], sc[0] + sc[1] + sc[2] + sc[3]);
    }
}

// ---------------- positive-part kernel ----------------
// ONE WAVE PER POINT: 768 points = 3 levels x B(2) x P(128).
// Lane l covers window elements l, l+64, l+128, l+192 (independent loads),
// then a __shfl_xor max-reduce; lane 0 does the logistic math + atomics.
__global__ __launch_bounds__(256) void focal_pos_kernel(
    const float* __restrict__ lg0, const int* __restrict__ co0,
    const float* __restrict__ lg1, const int* __restrict__ co1,
    const float* __restrict__ lg2, const int* __restrict__ co2,
    float* __restrict__ out)
{
    int gwave = (blockIdx.x * blockDim.x + threadIdx.x) >> 6;   // 0..767
    int lane  = threadIdx.x & 63;
    if (gwave >= 768) return;

    int lvl = gwave >> 8;        // 256 points / level
    int rem = gwave & 255;
    int b   = rem >> 7;          // 0..1
    int p   = rem & 127;
    const float* lg; const int* co; int D; int r; float factor;
    if (lvl == 0)      { lg = lg0; co = co0; D = 128; r = 1; factor = 4.0f; }
    else if (lvl == 1) { lg = lg1; co = co1; D = 64;  r = 2; factor = 2.0f; }
    else               { lg = lg2; co = co2; D = 32;  r = 3; factor = 1.0f; }

    const int* c = co + (b * 128 + p) * 4;
    int a = c[0], y = c[1], x = c[2], z = c[3];   // broadcast load (same addr all lanes)
    if (a <= -1) return;                          // wave-uniform

    const int A = 2;
    int ac = min(max(a, 0), A - 1);
    int yc = min(max(y, 0), D - 1);
    int xc = min(max(x, 0), D - 1);
    int zc = min(max(z, 0), D - 1);
    const float* base = lg + (size_t)(b * A + ac) * D * D * D;

    int w1 = 2 * r;                 // window edge
    int w3 = w1 * w1 * w1;          // <= 216
    float wmax = -INFINITY;
    for (int k = lane; k < w3; k += 64) {
        int dz = k % w1;
        int t  = k / w1;
        int dx = t % w1;
        int dy = t / w1;
        int iy = min(max(yc + dy - r, 0), D - 1);
        int ix = min(max(xc + dx - r, 0), D - 1);
        int iz = min(max(zc + dz - r, 0), D - 1);
        wmax = fmaxf(wmax, base[((size_t)iy * D + ix) * D + iz]);
    }
    #pragma unroll
    for (int off = 32; off > 0; off >>= 1)
        wmax = fmaxf(wmax, __shfl_xor(wmax, off));

    if (lane == 0) {
        float point = base[((size_t)yc * D + xc) * D + zc];
        bool near_low = (yc < r) || (xc < r) || (zc < r);
        float lp = near_low ? point : wmax;
        float t  = fexp(-fabsf(lp));
        float inv = frcp(1.0f + t);
        float s  = (lp >= 0.0f) ? inv : t * inv;    // sigmoid(lp)
        float omw = 1.0f - s;
        float w   = omw * omw;
        float nls = fmaxf(-lp, 0.0f) + flog(1.0f + t);  // -log_sigmoid(lp) = softplus(-lp)
        atomicAdd(&out[0], nls * w * factor);
        atomicAdd(&out[2], w);
    }
}

extern "C" void kernel_launch(void* const* d_in, const int* in_sizes, int n_in,
                              void* d_out, int out_size, void* d_ws, size_t ws_size,
                              hipStream_t stream) {
    const float* lg[3]; const float* pr[3]; const int* co[3];
    int nElem[3];
    if (n_in == 9 && in_sizes[1] == in_sizes[0]) {
        // setup_inputs() dict order: lg0,pr0,co0, lg1,pr1,co1, lg2,pr2,co2
        lg[0] = (const float*)d_in[0]; pr[0] = (const float*)d_in[1]; co[0] = (const int*)d_in[2];
        lg[1] = (const float*)d_in[3]; pr[1] = (const float*)d_in[4]; co[1] = (const int*)d_in[5];
        lg[2] = (const float*)d_in[6]; pr[2] = (const float*)d_in[7]; co[2] = (const int*)d_in[8];
        nElem[0] = in_sizes[0]; nElem[1] = in_sizes[3]; nElem[2] = in_sizes[6];
    } else {
        // reference signature order: lg0,lg1,lg2, pr0,pr1,pr2, co0,co1,co2
        lg[0] = (const float*)d_in[0]; lg[1] = (const float*)d_in[1]; lg[2] = (const float*)d_in[2];
        pr[0] = (const float*)d_in[3]; pr[1] = (const float*)d_in[4]; pr[2] = (const float*)d_in[5];
        co[0] = (const int*)d_in[6];   co[1] = (const int*)d_in[7];   co[2] = (const int*)d_in[8];
        nElem[0] = in_sizes[0]; nElem[1] = in_sizes[1]; nElem[2] = in_sizes[2];
    }
    float* out = (float*)d_out;
    hipMemsetAsync(out, 0, 4 * sizeof(float), stream);

    int n0 = nElem[0] / 4, n1 = nElem[1] / 4, n2 = nElem[2] / 4;
    int total = n0 + n1 + n2;
    int blocks = (total + 255) / 256;
    if (blocks > 2048) blocks = 2048;
    focal_neg_kernel<<<blocks, 256, 0, stream>>>(
        (const float4*)lg[0], (const float4*)pr[0], n0,
        (const float4*)lg[1], (const float4*)pr[1], n1,
        (const float4*)lg[2], (const float4*)pr[2], n2,
        out);
    // 768 waves = 192 blocks x 4 waves
    focal_pos_kernel<<<192, 256, 0, stream>>>(
        lg[0], co[0], lg[1], co[1], lg[2], co[2], out);
}

// Round 3
// 116.727 us; speedup vs baseline: 1.6484x; 1.4997x over previous
//
#include <hip/hip_runtime.h>
#include <math.h>

// ---------------- fast device math (HW transcendentals) ----------------
__device__ __forceinline__ float fexp(float x)  { return __expf(x); }   // v_exp_f32
__device__ __forceinline__ float flog(float x)  { return __logf(x); }   // v_log_f32
__device__ __forceinline__ float frcp(float x)  { return __builtin_amdgcn_rcpf(x); }

#define NB_NEG   1024     // neg-part blocks (grid-stride)
#define NBLK_POS 192      // pos-part blocks: 4 waves each -> 768 points
// ws layout (floats):
//   [0, NB_NEG)                 : neg loss partial, one per block
//   [NB_NEG, 2*NB_NEG)          : neg cnt  partial, one per block
//   [2*NB_NEG, 2*NB_NEG+768)    : pos loss partial, one per wave-point
//   [2*NB_NEG+768, 2*NB_NEG+1536): pos cnt partial, one per wave-point

__global__ __launch_bounds__(256) void focal_stage1(
    const float4* __restrict__ lg0, const float4* __restrict__ pr0, int n0,
    const float4* __restrict__ lg1, const float4* __restrict__ pr1, int n1,
    const float4* __restrict__ lg2, const float4* __restrict__ pr2, int n2,
    const float* __restrict__ lgs0, const int* __restrict__ co0,
    const float* __restrict__ lgs1, const int* __restrict__ co1,
    const float* __restrict__ lgs2, const int* __restrict__ co2,
    float* __restrict__ ws)
{
    const int lane = threadIdx.x & 63;
    if (blockIdx.x < NB_NEG) {
        // ---------------- negative part: block-strided streaming ----------------
        float loss = 0.0f, cnt = 0.0f;
        const int total  = n0 + n1 + n2;
        const int stride = NB_NEG * 256;
        for (int i = blockIdx.x * 256 + threadIdx.x; i < total; i += stride) {
            const float4* lgp; const float4* prp; int idx; float factor;
            if (i < n0)           { lgp = lg0; prp = pr0; idx = i;            factor = 4.0f; }
            else if (i < n0 + n1) { lgp = lg1; prp = pr1; idx = i - n0;       factor = 2.0f; }
            else                  { lgp = lg2; prp = pr2; idx = i - n0 - n1;  factor = 1.0f; }
            float4 l4 = lgp[idx];
            float4 p4 = prp[idx];
            const float* lv = (const float*)&l4;
            const float* pv = (const float*)&p4;
            #pragma unroll
            for (int j = 0; j < 4; ++j) {
                float l = lv[j];
                float m = (pv[j] == -1.0f) ? 1.0f : 0.0f;     // branchless mask
                float t = fexp(-fabsf(l));                    // e^{-|l|}
                float inv = frcp(1.0f + t);
                float s = (l >= 0.0f) ? inv : t * inv;        // sigmoid(l)
                float w = s * s * m;
                float sp = fmaxf(l, 0.0f) + flog(1.0f + t);   // softplus(l)
                cnt  += w;
                loss += sp * w * factor;
            }
        }
        #pragma unroll
        for (int off = 32; off > 0; off >>= 1) {
            loss += __shfl_down(loss, off);
            cnt  += __shfl_down(cnt,  off);
        }
        __shared__ float sl[4], sc[4];
        int wid = threadIdx.x >> 6;
        if (lane == 0) { sl[wid] = loss; sc[wid] = cnt; }
        __syncthreads();
        if (threadIdx.x == 0) {
            ws[blockIdx.x]          = sl[0] + sl[1] + sl[2] + sl[3];
            ws[NB_NEG + blockIdx.x] = sc[0] + sc[1] + sc[2] + sc[3];
        }
    } else {
        // ---------------- positive part: one wave per point ----------------
        int pb    = blockIdx.x - NB_NEG;
        int gwave = pb * 4 + (threadIdx.x >> 6);    // 0..767
        int lvl = gwave >> 8;
        int rem = gwave & 255;
        int b   = rem >> 7;
        int p   = rem & 127;
        const float* lg; const int* co; int D; int r; float factor;
        if (lvl == 0)      { lg = lgs0; co = co0; D = 128; r = 1; factor = 4.0f; }
        else if (lvl == 1) { lg = lgs1; co = co1; D = 64;  r = 2; factor = 2.0f; }
        else               { lg = lgs2; co = co2; D = 32;  r = 3; factor = 1.0f; }

        const int* c = co + (b * 128 + p) * 4;
        int a = c[0], y = c[1], x = c[2], z = c[3];   // broadcast load
        float loss = 0.0f, cnt = 0.0f;
        if (a > -1) {                                  // wave-uniform
            const int A = 2;
            int ac = min(max(a, 0), A - 1);
            int yc = min(max(y, 0), D - 1);
            int xc = min(max(x, 0), D - 1);
            int zc = min(max(z, 0), D - 1);
            const float* base = lg + (size_t)(b * A + ac) * D * D * D;
            int w1 = 2 * r;
            int w3 = w1 * w1 * w1;                    // <= 216
            float wmax = -INFINITY;
            for (int k = lane; k < w3; k += 64) {
                int dz = k % w1;
                int t  = k / w1;
                int dx = t % w1;
                int dy = t / w1;
                int iy = min(max(yc + dy - r, 0), D - 1);
                int ix = min(max(xc + dx - r, 0), D - 1);
                int iz = min(max(zc + dz - r, 0), D - 1);
                wmax = fmaxf(wmax, base[((size_t)iy * D + ix) * D + iz]);
            }
            #pragma unroll
            for (int off = 32; off > 0; off >>= 1)
                wmax = fmaxf(wmax, __shfl_xor(wmax, off));
            float point = base[((size_t)yc * D + xc) * D + zc];
            bool near_low = (yc < r) || (xc < r) || (zc < r);
            float lp = near_low ? point : wmax;
            float t  = fexp(-fabsf(lp));
            float inv = frcp(1.0f + t);
            float s  = (lp >= 0.0f) ? inv : t * inv;         // sigmoid(lp)
            float omw = 1.0f - s;
            float w   = omw * omw;
            float nls = fmaxf(-lp, 0.0f) + flog(1.0f + t);   // softplus(-lp)
            loss = nls * w * factor;
            cnt  = w;
        }
        if (lane == 0) {
            ws[2 * NB_NEG + gwave]       = loss;
            ws[2 * NB_NEG + 768 + gwave] = cnt;
        }
    }
}

// one block, 4 waves: wave k sums one segment, writes one output
__global__ __launch_bounds__(256) void focal_stage2(
    const float* __restrict__ ws, float* __restrict__ out)
{
    int wid  = threadIdx.x >> 6;
    int lane = threadIdx.x & 63;
    const float* seg; int n; int oidx;
    if (wid == 0)      { seg = ws;                  n = NB_NEG; oidx = 1; }  // neg loss
    else if (wid == 1) { seg = ws + NB_NEG;         n = NB_NEG; oidx = 3; }  // neg cnt
    else if (wid == 2) { seg = ws + 2 * NB_NEG;     n = 768;    oidx = 0; }  // pos loss
    else               { seg = ws + 2 * NB_NEG + 768; n = 768;  oidx = 2; }  // pos cnt
    float s = 0.0f;
    for (int i = lane; i < n; i += 64) s += seg[i];
    #pragma unroll
    for (int off = 32; off > 0; off >>= 1) s += __shfl_down(s, off);
    if (lane == 0) out[oidx] = s;
}

extern "C" void kernel_launch(void* const* d_in, const int* in_sizes, int n_in,
                              void* d_out, int out_size, void* d_ws, size_t ws_size,
                              hipStream_t stream) {
    const float* lg[3]; const float* pr[3]; const int* co[3];
    int nElem[3];
    if (n_in == 9 && in_sizes[1] == in_sizes[0]) {
        // setup_inputs() dict order: lg0,pr0,co0, lg1,pr1,co1, lg2,pr2,co2
        lg[0] = (const float*)d_in[0]; pr[0] = (const float*)d_in[1]; co[0] = (const int*)d_in[2];
        lg[1] = (const float*)d_in[3]; pr[1] = (const float*)d_in[4]; co[1] = (const int*)d_in[5];
        lg[2] = (const float*)d_in[6]; pr[2] = (const float*)d_in[7]; co[2] = (const int*)d_in[8];
        nElem[0] = in_sizes[0]; nElem[1] = in_sizes[3]; nElem[2] = in_sizes[6];
    } else {
        // reference signature order
        lg[0] = (const float*)d_in[0]; lg[1] = (const float*)d_in[1]; lg[2] = (const float*)d_in[2];
        pr[0] = (const float*)d_in[3]; pr[1] = (const float*)d_in[4]; pr[2] = (const float*)d_in[5];
        co[0] = (const int*)d_in[6];   co[1] = (const int*)d_in[7];   co[2] = (const int*)d_in[8];
        nElem[0] = in_sizes[0]; nElem[1] = in_sizes[1]; nElem[2] = in_sizes[2];
    }
    float* out = (float*)d_out;
    float* ws  = (float*)d_ws;

    int n0 = nElem[0] / 4, n1 = nElem[1] / 4, n2 = nElem[2] / 4;
    focal_stage1<<<NB_NEG + NBLK_POS, 256, 0, stream>>>(
        (const float4*)lg[0], (const float4*)pr[0], n0,
        (const float4*)lg[1], (const float4*)pr[1], n1,
        (const float4*)lg[2], (const float4*)pr[2], n2,
        lg[0], co[0], lg[1], co[1], lg[2], co[2],
        ws);
    focal_stage2<<<1, 256, 0, stream>>>(ws, out);
}

// Round 4
// 114.747 us; speedup vs baseline: 1.6768x; 1.0173x over previous
//
#include <hip/hip_runtime.h>
#include <math.h>

// ---------------- fast device math (HW transcendentals) ----------------
__device__ __forceinline__ float fexp(float x)  { return __expf(x); }   // v_exp_f32
__device__ __forceinline__ float flog(float x)  { return __logf(x); }   // v_log_f32
__device__ __forceinline__ float frcp(float x)  { return __builtin_amdgcn_rcpf(x); }

#define NB_NEG   1024     // neg-part blocks (grid-stride)
#define NBLK_POS 192      // pos-part blocks: 4 waves each -> 768 points
// ws layout (floats):
//   [0, NB_NEG)                  : neg loss partial, one per block
//   [NB_NEG, 2*NB_NEG)           : neg cnt  partial, one per block
//   [2*NB_NEG, 2*NB_NEG+768)     : pos loss partial, one per wave-point
//   [2*NB_NEG+768, 2*NB_NEG+1536): pos cnt partial, one per wave-point

// accumulate one float4 pair
__device__ __forceinline__ void neg_acc(float4 l4, float4 p4, float factor,
                                        float& loss, float& cnt) {
    const float* lv = (const float*)&l4;
    const float* pv = (const float*)&p4;
    #pragma unroll
    for (int j = 0; j < 4; ++j) {
        float l = lv[j];
        float m = (pv[j] == -1.0f) ? 1.0f : 0.0f;     // branchless mask
        float t = fexp(-fabsf(l));                    // e^{-|l|}
        float inv = frcp(1.0f + t);
        float s = (l >= 0.0f) ? inv : t * inv;        // sigmoid(l)
        float w = s * s * m;
        float sp = fmaxf(l, 0.0f) + flog(1.0f + t);   // softplus(l)
        cnt  += w;
        loss += sp * w * factor;
    }
}

__global__ __launch_bounds__(256) void focal_stage1(
    const float4* __restrict__ lg0, const float4* __restrict__ pr0, int n0,
    const float4* __restrict__ lg1, const float4* __restrict__ pr1, int n1,
    const float4* __restrict__ lg2, const float4* __restrict__ pr2, int n2,
    const float* __restrict__ lgs0, const int* __restrict__ co0,
    const float* __restrict__ lgs1, const int* __restrict__ co1,
    const float* __restrict__ lgs2, const int* __restrict__ co2,
    float* __restrict__ ws)
{
    const int lane = threadIdx.x & 63;
    if (blockIdx.x < NB_NEG) {
        // ------------- negative part: per-level loops, no branches -------------
        float loss = 0.0f, cnt = 0.0f;
        const int tid    = blockIdx.x * 256 + threadIdx.x;
        const int stride = NB_NEG * 256;
        // level 0 (factor 4): 2x unrolled -> 4 x 16B loads in flight
        int i = tid;
        for (; i + stride < n0; i += 2 * stride) {
            float4 a0 = lg0[i];          float4 b0 = pr0[i];
            float4 a1 = lg0[i + stride]; float4 b1 = pr0[i + stride];
            neg_acc(a0, b0, 4.0f, loss, cnt);
            neg_acc(a1, b1, 4.0f, loss, cnt);
        }
        for (; i < n0; i += stride) neg_acc(lg0[i], pr0[i], 4.0f, loss, cnt);
        // level 1 (factor 2)
        for (int k = tid; k < n1; k += stride) neg_acc(lg1[k], pr1[k], 2.0f, loss, cnt);
        // level 2 (factor 1)
        for (int k = tid; k < n2; k += stride) neg_acc(lg2[k], pr2[k], 1.0f, loss, cnt);

        #pragma unroll
        for (int off = 32; off > 0; off >>= 1) {
            loss += __shfl_down(loss, off);
            cnt  += __shfl_down(cnt,  off);
        }
        __shared__ float sl[4], sc[4];
        int wid = threadIdx.x >> 6;
        if (lane == 0) { sl[wid] = loss; sc[wid] = cnt; }
        __syncthreads();
        if (threadIdx.x == 0) {
            ws[blockIdx.x]          = sl[0] + sl[1] + sl[2] + sl[3];
            ws[NB_NEG + blockIdx.x] = sc[0] + sc[1] + sc[2] + sc[3];
        }
    } else {
        // ---------------- positive part: one wave per point ----------------
        int pb    = blockIdx.x - NB_NEG;
        int gwave = pb * 4 + (threadIdx.x >> 6);    // 0..767
        int lvl = gwave >> 8;
        int rem = gwave & 255;
        int b   = rem >> 7;
        int p   = rem & 127;
        const float* lg; const int* co; int D; int r; float factor;
        if (lvl == 0)      { lg = lgs0; co = co0; D = 128; r = 1; factor = 4.0f; }
        else if (lvl == 1) { lg = lgs1; co = co1; D = 64;  r = 2; factor = 2.0f; }
        else               { lg = lgs2; co = co2; D = 32;  r = 3; factor = 1.0f; }

        const int* c = co + (b * 128 + p) * 4;
        int a = c[0], y = c[1], x = c[2], z = c[3];   // broadcast load
        float loss = 0.0f, cnt = 0.0f;
        if (a > -1) {                                  // wave-uniform
            const int A = 2;
            int ac = min(max(a, 0), A - 1);
            int yc = min(max(y, 0), D - 1);
            int xc = min(max(x, 0), D - 1);
            int zc = min(max(z, 0), D - 1);
            const float* base = lg + (size_t)(b * A + ac) * D * D * D;
            int w1 = 2 * r;
            int w3 = w1 * w1 * w1;                    // <= 216
            float wmax = -INFINITY;
            for (int k = lane; k < w3; k += 64) {
                int dz = k % w1;
                int t  = k / w1;
                int dx = t % w1;
                int dy = t / w1;
                int iy = min(max(yc + dy - r, 0), D - 1);
                int ix = min(max(xc + dx - r, 0), D - 1);
                int iz = min(max(zc + dz - r, 0), D - 1);
                wmax = fmaxf(wmax, base[((size_t)iy * D + ix) * D + iz]);
            }
            #pragma unroll
            for (int off = 32; off > 0; off >>= 1)
                wmax = fmaxf(wmax, __shfl_xor(wmax, off));
            float point = base[((size_t)yc * D + xc) * D + zc];
            bool near_low = (yc < r) || (xc < r) || (zc < r);
            float lp = near_low ? point : wmax;
            float t  = fexp(-fabsf(lp));
            float inv = frcp(1.0f + t);
            float s  = (lp >= 0.0f) ? inv : t * inv;         // sigmoid(lp)
            float omw = 1.0f - s;
            float w   = omw * omw;
            float nls = fmaxf(-lp, 0.0f) + flog(1.0f + t);   // softplus(-lp)
            loss = nls * w * factor;
            cnt  = w;
        }
        if (lane == 0) {
            ws[2 * NB_NEG + gwave]       = loss;
            ws[2 * NB_NEG + 768 + gwave] = cnt;
        }
    }
}

// one block, 4 waves: wave k sums one segment, writes one output
__global__ __launch_bounds__(256) void focal_stage2(
    const float* __restrict__ ws, float* __restrict__ out)
{
    int wid  = threadIdx.x >> 6;
    int lane = threadIdx.x & 63;
    const float* seg; int n; int oidx;
    if (wid == 0)      { seg = ws;                    n = NB_NEG; oidx = 1; }  // neg loss
    else if (wid == 1) { seg = ws + NB_NEG;           n = NB_NEG; oidx = 3; }  // neg cnt
    else if (wid == 2) { seg = ws + 2 * NB_NEG;       n = 768;    oidx = 0; }  // pos loss
    else               { seg = ws + 2 * NB_NEG + 768; n = 768;    oidx = 2; }  // pos cnt
    float s = 0.0f;
    for (int i = lane; i < n; i += 64) s += seg[i];
    #pragma unroll
    for (int off = 32; off > 0; off >>= 1) s += __shfl_down(s, off);
    if (lane == 0) out[oidx] = s;
}

extern "C" void kernel_launch(void* const* d_in, const int* in_sizes, int n_in,
                              void* d_out, int out_size, void* d_ws, size_t ws_size,
                              hipStream_t stream) {
    const float* lg[3]; const float* pr[3]; const int* co[3];
    int nElem[3];
    if (n_in == 9 && in_sizes[1] == in_sizes[0]) {
        // setup_inputs() dict order: lg0,pr0,co0, lg1,pr1,co1, lg2,pr2,co2
        lg[0] = (const float*)d_in[0]; pr[0] = (const float*)d_in[1]; co[0] = (const int*)d_in[2];
        lg[1] = (const float*)d_in[3]; pr[1] = (const float*)d_in[4]; co[1] = (const int*)d_in[5];
        lg[2] = (const float*)d_in[6]; pr[2] = (const float*)d_in[7]; co[2] = (const int*)d_in[8];
        nElem[0] = in_sizes[0]; nElem[1] = in_sizes[3]; nElem[2] = in_sizes[6];
    } else {
        // reference signature order
        lg[0] = (const float*)d_in[0]; lg[1] = (const float*)d_in[1]; lg[2] = (const float*)d_in[2];
        pr[0] = (const float*)d_in[3]; pr[1] = (const float*)d_in[4]; pr[2] = (const float*)d_in[5];
        co[0] = (const int*)d_in[6];   co[1] = (const int*)d_in[7];   co[2] = (const int*)d_in[8];
        nElem[0] = in_sizes[0]; nElem[1] = in_sizes[1]; nElem[2] = in_sizes[2];
    }
    float* out = (float*)d_out;
    float* ws  = (float*)d_ws;

    int n0 = nElem[0] / 4, n1 = nElem[1] / 4, n2 = nElem[2] / 4;
    focal_stage1<<<NB_NEG + NBLK_POS, 256, 0, stream>>>(
        (const float4*)lg[0], (const float4*)pr[0], n0,
        (const float4*)lg[1], (const float4*)pr[1], n1,
        (const float4*)lg[2], (const float4*)pr[2], n2,
        lg[0], co[0], lg[1], co[1], lg[2], co[2],
        ws);
    focal_stage2<<<1, 256, 0, stream>>>(ws, out);
}